// Round 2
// baseline (611.242 us; speedup 1.0000x reference)
//
#include <hip/hip_runtime.h>

#define N_NODES 100000
#define N_EDGES 640000
#define D 128
#define SCAN_TILE 1024
#define SCAN_BLOCKS ((N_NODES + SCAN_TILE - 1) / SCAN_TILE)  // 98

typedef __attribute__((ext_vector_type(8))) short bf16x8;   // 8 bf16 = 4 VGPRs
typedef __attribute__((ext_vector_type(4))) float f32x4;

__device__ __forceinline__ unsigned short f32_to_bf16(float f) {
  union { float f; unsigned int u; } v; v.f = f;
  unsigned int u = v.u;
  unsigned int r = (u + 0x7fffu + ((u >> 16) & 1u)) >> 16;  // RNE
  return (unsigned short)r;
}
__device__ __forceinline__ float bf16_lo(unsigned int u) { return __uint_as_float(u << 16); }
__device__ __forceinline__ float bf16_hi(unsigned int u) { return __uint_as_float(u & 0xffff0000u); }

__device__ __forceinline__ void acc8(float* a, uint4 r) {
  a[0] += bf16_lo(r.x); a[1] += bf16_hi(r.x);
  a[2] += bf16_lo(r.y); a[3] += bf16_hi(r.y);
  a[4] += bf16_lo(r.z); a[5] += bf16_hi(r.z);
  a[6] += bf16_lo(r.w); a[7] += bf16_hi(r.w);
}

// ---------------------------------------------------------------- utilities
__global__ void zero_i32(int* __restrict__ p, int n) {
  int i = blockIdx.x * blockDim.x + threadIdx.x;
  if (i < n) p[i] = 0;
}

__global__ void f32_to_bf16_vec(const float* __restrict__ in, unsigned short* __restrict__ out, int n4) {
  int i = blockIdx.x * blockDim.x + threadIdx.x;
  if (i < n4) {
    float4 v = ((const float4*)in)[i];
    ushort4 o;
    o.x = f32_to_bf16(v.x); o.y = f32_to_bf16(v.y);
    o.z = f32_to_bf16(v.z); o.w = f32_to_bf16(v.w);
    ((ushort4*)out)[i] = o;
  }
}

// 8 weight matrices [128x128] fp32 row-major [k][n] -> bf16 transposed Wt[n][k]
__global__ void transpose_w(const float* __restrict__ W0, const float* __restrict__ W1,
                            const float* __restrict__ W2, const float* __restrict__ W3,
                            const float* __restrict__ W4, const float* __restrict__ W5,
                            const float* __restrict__ W6, const float* __restrict__ W7,
                            unsigned short* __restrict__ wt) {
  int id = blockIdx.x * 256 + threadIdx.x;  // 512 blocks x 256 = 131072
  int mat = id >> 14;
  int rem = id & 16383;
  int n = rem >> 7, k = rem & 127;
  const float* Wm = mat < 4 ? (mat < 2 ? (mat == 0 ? W0 : W1) : (mat == 2 ? W2 : W3))
                            : (mat < 6 ? (mat == 4 ? W4 : W5) : (mat == 6 ? W6 : W7));
  wt[id] = f32_to_bf16(Wm[k * D + n]);
}

// ------------------------------------------------------------- CSR building (pos edges only)
__global__ void hist_kernel(const int* __restrict__ dst, int* __restrict__ deg, int E) {
  int i = blockIdx.x * blockDim.x + threadIdx.x;
  if (i < E) atomicAdd(&deg[dst[i]], 1);
}

__global__ void scan_blocksum(const int* __restrict__ deg, int* __restrict__ partial, int n) {
  __shared__ int lds[256];
  const int tid = threadIdx.x;
  const int base = blockIdx.x * SCAN_TILE + tid * 4;
  int s = 0;
#pragma unroll
  for (int j = 0; j < 4; ++j) {
    int i = base + j;
    if (i < n) s += deg[i];
  }
  lds[tid] = s;
  __syncthreads();
  for (int off = 128; off > 0; off >>= 1) {
    if (tid < off) lds[tid] += lds[tid + off];
    __syncthreads();
  }
  if (tid == 0) partial[blockIdx.x] = lds[0];
}

__global__ void scan_offsets(int* __restrict__ partial, int* __restrict__ row_start, int nb, int n) {
  __shared__ int lds[128];
  const int tid = threadIdx.x;
  int v = (tid < nb) ? partial[tid] : 0;
  lds[tid] = v;
  __syncthreads();
  for (int off = 1; off < 128; off <<= 1) {
    int t = (tid >= off) ? lds[tid - off] : 0;
    __syncthreads();
    lds[tid] += t;
    __syncthreads();
  }
  if (tid < nb) partial[tid] = (tid == 0) ? 0 : lds[tid - 1];
  if (tid == 0) row_start[n] = lds[nb - 1];
}

__global__ void scan_final(const int* __restrict__ deg, const int* __restrict__ partial,
                           int* __restrict__ row_start, int n) {
  __shared__ int lds[256];
  const int tid = threadIdx.x;
  const int base = blockIdx.x * SCAN_TILE + tid * 4;
  int d[4];
  int s = 0;
#pragma unroll
  for (int j = 0; j < 4; ++j) {
    int i = base + j;
    d[j] = (i < n) ? deg[i] : 0;
    s += d[j];
  }
  lds[tid] = s;
  __syncthreads();
  for (int off = 1; off < 256; off <<= 1) {
    int t = (tid >= off) ? lds[tid - off] : 0;
    __syncthreads();
    lds[tid] += t;
    __syncthreads();
  }
  int pre = partial[blockIdx.x] + lds[tid] - s;
#pragma unroll
  for (int j = 0; j < 4; ++j) {
    int i = base + j;
    if (i < n) {
      row_start[i] = pre;
      pre += d[j];
    }
  }
}

__global__ void fill_kernel(const int* __restrict__ src, const int* __restrict__ dst,
                            const int* __restrict__ row_start, int* __restrict__ cursor,
                            int* __restrict__ esrc, int E) {
  int i = blockIdx.x * blockDim.x + threadIdx.x;
  if (i < E) {
    int d = dst[i];
    int pos = atomicAdd(&cursor[d], 1);
    esrc[row_start[d] + pos] = src[i];
  }
}

// ----------------------------------------------------- fused SAGE layer
// Block = 64 nodes, 4 waves, wave w owns output rows 16w..16w+15.
// Phase 1: gather mean(h[neigh]) -> mt rows owned by this wave (no barrier:
// wave w's groups 4w+q write exactly rows 16w..16w+15, which only wave w reads).
// Phase 2: out = h@Ws + mean@Wn + b via MFMA. B-fragments are loaded DIRECTLY
// from global (L2-hot: 32 KB/matrix shared by all blocks) -- no LDS staging,
// no stage barriers. Round-1 counters showed the 9-barrier staged version was
// latency-bound (MfmaUtil 6%, VALUBusy 21%, HBM 21%, occ 24%): barriers
// lockstepped all waves through 16 KB stages. Now waves are fully decoupled;
// the ONLY barrier is inside the epilogue transpose.
// EPILOGUE: coalesced via LDS transpose (scattered 2B stores cost 2x write amp).
// PRED variant (layer 3): keep h3 in LDS, two more weight matrices produce
// A = h3@WtA + biasA and B = h3@WtB directly (h3 never hits HBM).
template <bool PRED>
__global__ __launch_bounds__(256) void layer_fused(
    const unsigned short* __restrict__ hin,
    const int* __restrict__ row_start, const int* __restrict__ esrc,
    const unsigned short* __restrict__ Wts, const unsigned short* __restrict__ Wtn,
    const float* __restrict__ bias,
    const unsigned short* __restrict__ WtA, const unsigned short* __restrict__ WtB,
    const float* __restrict__ biasA,
    unsigned short* __restrict__ out0, unsigned short* __restrict__ out1, int M) {
  __shared__ unsigned short mt[64][136];   // 17.4 KB mean tile (reused: h3 tile, epilogue tile)
  const int tid = threadIdx.x;
  const int lane = tid & 63;
  const int wave = tid >> 6;
  const int m0 = blockIdx.x * 64;
  const int row = lane & 15;
  const int q = lane >> 4;
  const int mw = m0 + wave * 16;
  const int mload = min(mw + row, M - 1);

  // per-lane base offset into a transposed weight matrix (shorts):
  // frag(W,half,t,s) = W[(half*64 + t*16 + row)*D + s*32 + q*8]
  const size_t wb = (size_t)row * D + q * 8;

  // 16 MFMAs of one half-n panel, B-frags straight from global (L2)
  auto mfma_half = [&](const unsigned short* Wt, int half, bf16x8* a, f32x4* accp) {
#pragma unroll
    for (int s = 0; s < 4; ++s)
#pragma unroll
      for (int t = 0; t < 4; ++t) {
        bf16x8 b = *reinterpret_cast<const bf16x8*>(
            Wt + wb + (size_t)(half * 64 + t * 16) * D + s * 32);
        accp[t] = __builtin_amdgcn_mfma_f32_16x16x32_bf16(a[s], b, accp[t], 0, 0, 0);
      }
  };
  // coalesced epilogue: acc (+bias) -> mt -> barrier -> contiguous uint4 stores.
  // Preconditions: all waves' previous readers of mt are done (own-row writes
  // are always safe; the internal barrier protects the all-row reads).
  auto epilogue = [&](f32x4* accp, const float* bvec, unsigned short* dst) {
#pragma unroll
    for (int t = 0; t < 8; ++t) {
      const int col = t * 16 + row;
      const float bv = bvec ? bvec[col] : 0.f;
#pragma unroll
      for (int r = 0; r < 4; ++r)
        mt[wave * 16 + q * 4 + r][col] = f32_to_bf16(accp[t][r] + bv);
    }
    __syncthreads();
    // full tile = 64 rows x 16 chunks of 16B = 1024 chunks, 4 per thread
#pragma unroll
    for (int i = 0; i < 4; ++i) {
      int idx = i * 256 + tid;
      int r2 = idx >> 4;
      int c8 = (idx & 15) * 8;
      int m = m0 + r2;
      if (m < M)
        *reinterpret_cast<uint4*>(dst + (size_t)m * D + c8) =
            *reinterpret_cast<const uint4*>(&mt[r2][c8]);
    }
  };

  // ---- A fragments of hin ----
  bf16x8 ah[4];
#pragma unroll
  for (int s = 0; s < 4; ++s)
    ah[s] = *reinterpret_cast<const bf16x8*>(hin + (size_t)mload * D + s * 32 + q * 8);

  // ---- phase 1: gather means into mt. group g (16 lanes) handles 4 nodes.
  // wave w = groups 4w..4w+3 -> writes rows 16w..16w+15 only (own rows).
  {
    const int g = tid >> 4;   // 0..15
    const int fl = tid & 15;  // feature lane, 16 B each
    for (int j = 0; j < 4; ++j) {
      const int node = m0 + g * 4 + j;
      float ac[8] = {0.f, 0.f, 0.f, 0.f, 0.f, 0.f, 0.f, 0.f};
      if (node < M) {
        const int s0 = row_start[node], s1 = row_start[node + 1];
        int e = s0;
        for (; e + 4 <= s1; e += 4) {
          int i0 = esrc[e], i1 = esrc[e + 1], i2 = esrc[e + 2], i3 = esrc[e + 3];
          uint4 r0 = *(const uint4*)(hin + (size_t)i0 * D + fl * 8);
          uint4 r1 = *(const uint4*)(hin + (size_t)i1 * D + fl * 8);
          uint4 r2 = *(const uint4*)(hin + (size_t)i2 * D + fl * 8);
          uint4 r3 = *(const uint4*)(hin + (size_t)i3 * D + fl * 8);
          acc8(ac, r0); acc8(ac, r1); acc8(ac, r2); acc8(ac, r3);
        }
        for (; e < s1; ++e) {
          uint4 r0 = *(const uint4*)(hin + (size_t)esrc[e] * D + fl * 8);
          acc8(ac, r0);
        }
        const float inv = 1.0f / (float)max(s1 - s0, 1);
#pragma unroll
        for (int k = 0; k < 8; ++k) ac[k] *= inv;
      }
      uint4 o;
      o.x = (unsigned)f32_to_bf16(ac[0]) | ((unsigned)f32_to_bf16(ac[1]) << 16);
      o.y = (unsigned)f32_to_bf16(ac[2]) | ((unsigned)f32_to_bf16(ac[3]) << 16);
      o.z = (unsigned)f32_to_bf16(ac[4]) | ((unsigned)f32_to_bf16(ac[5]) << 16);
      o.w = (unsigned)f32_to_bf16(ac[6]) | ((unsigned)f32_to_bf16(ac[7]) << 16);
      *reinterpret_cast<uint4*>(&mt[g * 4 + j][fl * 8]) = o;
    }
  }
  // NO barrier: each wave reads back only the mt rows it wrote (lgkmcnt orders
  // same-wave LDS write->read).

  // ---- mean A-fragments from LDS (own rows) ----
  const int lrow = wave * 16 + row;  // local row 0..63
  bf16x8 am[4];
#pragma unroll
  for (int s = 0; s < 4; ++s)
    am[s] = *reinterpret_cast<const bf16x8*>(&mt[lrow][s * 32 + q * 8]);

  f32x4 acc[8];
#pragma unroll
  for (int t = 0; t < 8; ++t) acc[t] = (f32x4){0.f, 0.f, 0.f, 0.f};

  mfma_half(Wts, 0, ah, acc);         // hin @ Ws, n 0..63
  mfma_half(Wts, 1, ah, acc + 4);     // hin @ Ws, n 64..127
  mfma_half(Wtn, 0, am, acc);         // mean @ Wn, n 0..63
  mfma_half(Wtn, 1, am, acc + 4);     // mean @ Wn, n 64..127

  if (!PRED) {
    epilogue(acc, bias, out0);
    return;
  }

  // ================= PRED tail (layer 3) =================
  // h3 (bf16, bias applied) -> mt own rows (am already in regs; other waves
  // never read our rows), then ap from own rows -- still no barrier.
#pragma unroll
  for (int t = 0; t < 8; ++t) {
    const int col = t * 16 + row;
    const float bv = bias[col];
#pragma unroll
    for (int r = 0; r < 4; ++r)
      mt[wave * 16 + q * 4 + r][col] = f32_to_bf16(acc[t][r] + bv);
  }
  bf16x8 ap[4];
#pragma unroll
  for (int s = 0; s < 4; ++s)
    ap[s] = *reinterpret_cast<const bf16x8*>(&mt[lrow][s * 32 + q * 8]);

#pragma unroll
  for (int t = 0; t < 8; ++t) acc[t] = (f32x4){0.f, 0.f, 0.f, 0.f};
  mfma_half(WtA, 0, ap, acc);         // h3 @ WtA, n 0..63
  mfma_half(WtA, 1, ap, acc + 4);     // h3 @ WtA, n 64..127
  epilogue(acc, biasA, out0);         // Ab coalesced
  __syncthreads();  // all waves' epilogue-A mt reads done before overwrite
#pragma unroll
  for (int t = 0; t < 8; ++t) acc[t] = (f32x4){0.f, 0.f, 0.f, 0.f};
  mfma_half(WtB, 0, ap, acc);         // h3 @ WtB, n 0..63
  mfma_half(WtB, 1, ap, acc + 4);     // h3 @ WtB, n 64..127
  epilogue(acc, nullptr, out1);       // Bb coalesced
}

// ----------------------------------------------------- edge MLP score, 4 edges / 16-lane group
// score = relu(A[s]+B[d]).Wp2 + bp2  (bp1 folded into A). 8 row-gathers in
// flight per group, int4 index loads, one coalesced float4 store per group.
__device__ __forceinline__ float relu_dot8(uint4 a, uint4 b, float4 w0, float4 w1) {
  return fmaxf(bf16_lo(a.x) + bf16_lo(b.x), 0.f) * w0.x +
         fmaxf(bf16_hi(a.x) + bf16_hi(b.x), 0.f) * w0.y +
         fmaxf(bf16_lo(a.y) + bf16_lo(b.y), 0.f) * w0.z +
         fmaxf(bf16_hi(a.y) + bf16_hi(b.y), 0.f) * w0.w +
         fmaxf(bf16_lo(a.z) + bf16_lo(b.z), 0.f) * w1.x +
         fmaxf(bf16_hi(a.z) + bf16_hi(b.z), 0.f) * w1.y +
         fmaxf(bf16_lo(a.w) + bf16_lo(b.w), 0.f) * w1.z +
         fmaxf(bf16_hi(a.w) + bf16_hi(b.w), 0.f) * w1.w;
}

__global__ __launch_bounds__(256) void edge_score4(
    const unsigned short* __restrict__ A, const unsigned short* __restrict__ B,
    const int* __restrict__ ss, const int* __restrict__ dd,
    const float* __restrict__ Wp2, const float* __restrict__ bp2,
    float* __restrict__ out, int E) {
  const int t = blockIdx.x * blockDim.x + threadIdx.x;
  const int g = t >> 4;                 // 16 lanes per 4 edges
  const int fl = t & 15;
  const int e0 = g * 4;
  if (e0 >= E) return;
  const int4 s4 = *(const int4*)(ss + e0);
  const int4 d4 = *(const int4*)(dd + e0);
  const float4 w0 = *(const float4*)(Wp2 + fl * 8);
  const float4 w1 = *(const float4*)(Wp2 + fl * 8 + 4);
  const size_t fo = (size_t)(fl * 8);

  uint4 a0 = *(const uint4*)(A + (((size_t)s4.x << 7) + fo));
  uint4 b0 = *(const uint4*)(B + (((size_t)d4.x << 7) + fo));
  uint4 a1 = *(const uint4*)(A + (((size_t)s4.y << 7) + fo));
  uint4 b1 = *(const uint4*)(B + (((size_t)d4.y << 7) + fo));
  uint4 a2 = *(const uint4*)(A + (((size_t)s4.z << 7) + fo));
  uint4 b2 = *(const uint4*)(B + (((size_t)d4.z << 7) + fo));
  uint4 a3 = *(const uint4*)(A + (((size_t)s4.w << 7) + fo));
  uint4 b3 = *(const uint4*)(B + (((size_t)d4.w << 7) + fo));

  float p0 = relu_dot8(a0, b0, w0, w1);
  float p1 = relu_dot8(a1, b1, w0, w1);
  float p2 = relu_dot8(a2, b2, w0, w1);
  float p3 = relu_dot8(a3, b3, w0, w1);

  p0 += __shfl_xor(p0, 1); p1 += __shfl_xor(p1, 1); p2 += __shfl_xor(p2, 1); p3 += __shfl_xor(p3, 1);
  p0 += __shfl_xor(p0, 2); p1 += __shfl_xor(p1, 2); p2 += __shfl_xor(p2, 2); p3 += __shfl_xor(p3, 2);
  p0 += __shfl_xor(p0, 4); p1 += __shfl_xor(p1, 4); p2 += __shfl_xor(p2, 4); p3 += __shfl_xor(p3, 4);
  p0 += __shfl_xor(p0, 8); p1 += __shfl_xor(p1, 8); p2 += __shfl_xor(p2, 8); p3 += __shfl_xor(p3, 8);

  if (fl == 0) {
    const float bv = bp2[0];
    *reinterpret_cast<float4*>(out + e0) = make_float4(p0 + bv, p1 + bv, p2 + bv, p3 + bv);
  }
}

// ---------------------------------------------------------------- launcher
extern "C" void kernel_launch(void* const* d_in, const int* in_sizes, int n_in,
                              void* d_out, int out_size, void* d_ws, size_t ws_size,
                              hipStream_t stream) {
  const float* x = (const float*)d_in[0];
  const int* src = (const int*)d_in[1];
  const int* dst = (const int*)d_in[2];
  const int* nsrc = (const int*)d_in[3];
  const int* ndst = (const int*)d_in[4];
  const float* Ws1 = (const float*)d_in[5];
  const float* Wn1 = (const float*)d_in[6];
  const float* b1 = (const float*)d_in[7];
  const float* Ws2 = (const float*)d_in[8];
  const float* Wn2 = (const float*)d_in[9];
  const float* b2 = (const float*)d_in[10];
  const float* Ws3 = (const float*)d_in[11];
  const float* Wn3 = (const float*)d_in[12];
  const float* b3 = (const float*)d_in[13];
  const float* Wp1 = (const float*)d_in[14];
  const float* bp1 = (const float*)d_in[15];
  const float* Wp2 = (const float*)d_in[16];
  const float* bp2 = (const float*)d_in[17];
  float* out = (float*)d_out;

  char* ws = (char*)d_ws;
  size_t off = 0;
  auto alloc = [&](size_t bytes) -> void* {
    void* p = ws + off;
    off += (bytes + 255) & ~(size_t)255;
    return p;
  };
  const size_t NODE_F32 = sizeof(float) * (size_t)N_NODES * D;  // 51.2 MB
  char* region0 = (char*)alloc(NODE_F32);   // bf16 xb | (spare) -> later bf16 Ab | Bb
  char* region1 = (char*)alloc(NODE_F32);   // bf16 hA | hB
  int* row_start = (int*)alloc(sizeof(int) * (N_NODES + 1));
  int* deg = (int*)alloc(sizeof(int) * N_NODES * 2);  // deg + cursor
  int* cursor = deg + N_NODES;
  int* esrc = (int*)alloc(sizeof(int) * N_EDGES);
  int* partial = (int*)alloc(sizeof(int) * 128);
  unsigned short* wt = (unsigned short*)alloc(sizeof(unsigned short) * 8 * D * D);
  (void)ws_size;

  unsigned short* xb = (unsigned short*)region0;
  unsigned short* hA = (unsigned short*)region1;
  unsigned short* hB = hA + (size_t)N_NODES * D;
  unsigned short* Ab = xb;                              // xb dead after layer-1 kernel
  unsigned short* Bb = xb + (size_t)N_NODES * D;        // second half of region0 (unused otherwise)

  // ---- conversions
  f32_to_bf16_vec<<<(N_NODES * D / 4 + 255) / 256, 256, 0, stream>>>(x, xb, N_NODES * D / 4);
  transpose_w<<<512, 256, 0, stream>>>(Ws1, Wn1, Ws2, Wn2, Ws3, Wn3, Wp1, Wp1 + D * D, wt);

  // ---- CSR build (pos edges; reused by all 3 layers)
  zero_i32<<<(2 * N_NODES + 255) / 256, 256, 0, stream>>>(deg, 2 * N_NODES);
  hist_kernel<<<(N_EDGES + 255) / 256, 256, 0, stream>>>(dst, deg, N_EDGES);
  scan_blocksum<<<SCAN_BLOCKS, 256, 0, stream>>>(deg, partial, N_NODES);
  scan_offsets<<<1, 128, 0, stream>>>(partial, row_start, SCAN_BLOCKS, N_NODES);
  scan_final<<<SCAN_BLOCKS, 256, 0, stream>>>(deg, partial, row_start, N_NODES);
  fill_kernel<<<(N_EDGES + 255) / 256, 256, 0, stream>>>(src, dst, row_start, cursor, esrc, N_EDGES);

  const int layerBlocks = (N_NODES + 63) / 64;
  const int edgeBlocks = (N_EDGES / 4 * 16) / 256;  // 16 lanes per 4 edges = 10000

  // ---- layer 1: h1 = x@Ws1 + mean(x)@Wn1 + b1  (mean via LDS)
  layer_fused<false><<<layerBlocks, 256, 0, stream>>>(
      xb, row_start, esrc, wt, wt + 16384, b1, nullptr, nullptr, nullptr, hA, nullptr, N_NODES);
  // ---- layer 2
  layer_fused<false><<<layerBlocks, 256, 0, stream>>>(
      hA, row_start, esrc, wt + 2 * 16384, wt + 3 * 16384, b2, nullptr, nullptr, nullptr, hB, nullptr, N_NODES);
  // ---- layer 3 + predictor: Ab = h3@Wp1_top + bp1, Bb = h3@Wp1_bot (h3 never leaves LDS)
  layer_fused<true><<<layerBlocks, 256, 0, stream>>>(
      hB, row_start, esrc, wt + 4 * 16384, wt + 5 * 16384, b3, wt + 6 * 16384, wt + 7 * 16384, bp1,
      Ab, Bb, N_NODES);
  // ---- edge scores: pos then neg (independent; disjoint outputs)
  edge_score4<<<edgeBlocks, 256, 0, stream>>>(Ab, Bb, src, dst, Wp2, bp2, out, N_EDGES);
  edge_score4<<<edgeBlocks, 256, 0, stream>>>(Ab, Bb, nsrc, ndst, Wp2, bp2, out + N_EDGES, N_EDGES);
}

// Round 4
// 600.760 us; speedup vs baseline: 1.0174x; 1.0174x over previous
//
#include <hip/hip_runtime.h>

#define N_NODES 100000
#define N_EDGES 640000
#define D 128
#define SCAN_TILE 1024
#define SCAN_BLOCKS ((N_NODES + SCAN_TILE - 1) / SCAN_TILE)  // 98

typedef __attribute__((ext_vector_type(8))) short bf16x8;   // 8 bf16 = 4 VGPRs
typedef __attribute__((ext_vector_type(4))) float f32x4;

__device__ __forceinline__ unsigned short f32_to_bf16(float f) {
  union { float f; unsigned int u; } v; v.f = f;
  unsigned int u = v.u;
  unsigned int r = (u + 0x7fffu + ((u >> 16) & 1u)) >> 16;  // RNE
  return (unsigned short)r;
}
__device__ __forceinline__ float bf16_lo(unsigned int u) { return __uint_as_float(u << 16); }
__device__ __forceinline__ float bf16_hi(unsigned int u) { return __uint_as_float(u & 0xffff0000u); }

__device__ __forceinline__ void acc8(float* a, uint4 r) {
  a[0] += bf16_lo(r.x); a[1] += bf16_hi(r.x);
  a[2] += bf16_lo(r.y); a[3] += bf16_hi(r.y);
  a[4] += bf16_lo(r.z); a[5] += bf16_hi(r.z);
  a[6] += bf16_lo(r.w); a[7] += bf16_hi(r.w);
}

// ---------------------------------------------------------------- utilities
__global__ void zero_i32(int* __restrict__ p, int n) {
  int i = blockIdx.x * blockDim.x + threadIdx.x;
  if (i < n) p[i] = 0;
}

__global__ void f32_to_bf16_vec(const float* __restrict__ in, unsigned short* __restrict__ out, int n4) {
  int i = blockIdx.x * blockDim.x + threadIdx.x;
  if (i < n4) {
    float4 v = ((const float4*)in)[i];
    ushort4 o;
    o.x = f32_to_bf16(v.x); o.y = f32_to_bf16(v.y);
    o.z = f32_to_bf16(v.z); o.w = f32_to_bf16(v.w);
    ((ushort4*)out)[i] = o;
  }
}

// 8 weight matrices [128x128] fp32 row-major [k][n] -> bf16 transposed Wt[n][k]
__global__ void transpose_w(const float* __restrict__ W0, const float* __restrict__ W1,
                            const float* __restrict__ W2, const float* __restrict__ W3,
                            const float* __restrict__ W4, const float* __restrict__ W5,
                            const float* __restrict__ W6, const float* __restrict__ W7,
                            unsigned short* __restrict__ wt) {
  int id = blockIdx.x * 256 + threadIdx.x;  // 512 blocks x 256 = 131072
  int mat = id >> 14;
  int rem = id & 16383;
  int n = rem >> 7, k = rem & 127;
  const float* Wm = mat < 4 ? (mat < 2 ? (mat == 0 ? W0 : W1) : (mat == 2 ? W2 : W3))
                            : (mat < 6 ? (mat == 4 ? W4 : W5) : (mat == 6 ? W6 : W7));
  wt[id] = f32_to_bf16(Wm[k * D + n]);
}

// ------------------------------------------------------------- CSR building (pos edges only)
__global__ void hist_kernel(const int* __restrict__ dst, int* __restrict__ deg, int E) {
  int i = blockIdx.x * blockDim.x + threadIdx.x;
  if (i < E) atomicAdd(&deg[dst[i]], 1);
}

__global__ void scan_blocksum(const int* __restrict__ deg, int* __restrict__ partial, int n) {
  __shared__ int lds[256];
  const int tid = threadIdx.x;
  const int base = blockIdx.x * SCAN_TILE + tid * 4;
  int s = 0;
#pragma unroll
  for (int j = 0; j < 4; ++j) {
    int i = base + j;
    if (i < n) s += deg[i];
  }
  lds[tid] = s;
  __syncthreads();
  for (int off = 128; off > 0; off >>= 1) {
    if (tid < off) lds[tid] += lds[tid + off];
    __syncthreads();
  }
  if (tid == 0) partial[blockIdx.x] = lds[0];
}

__global__ void scan_offsets(int* __restrict__ partial, int* __restrict__ row_start, int nb, int n) {
  __shared__ int lds[128];
  const int tid = threadIdx.x;
  int v = (tid < nb) ? partial[tid] : 0;
  lds[tid] = v;
  __syncthreads();
  for (int off = 1; off < 128; off <<= 1) {
    int t = (tid >= off) ? lds[tid - off] : 0;
    __syncthreads();
    lds[tid] += t;
    __syncthreads();
  }
  if (tid < nb) partial[tid] = (tid == 0) ? 0 : lds[tid - 1];
  if (tid == 0) row_start[n] = lds[nb - 1];
}

__global__ void scan_final(const int* __restrict__ deg, const int* __restrict__ partial,
                           int* __restrict__ row_start, int n) {
  __shared__ int lds[256];
  const int tid = threadIdx.x;
  const int base = blockIdx.x * SCAN_TILE + tid * 4;
  int d[4];
  int s = 0;
#pragma unroll
  for (int j = 0; j < 4; ++j) {
    int i = base + j;
    d[j] = (i < n) ? deg[i] : 0;
    s += d[j];
  }
  lds[tid] = s;
  __syncthreads();
  for (int off = 1; off < 256; off <<= 1) {
    int t = (tid >= off) ? lds[tid - off] : 0;
    __syncthreads();
    lds[tid] += t;
    __syncthreads();
  }
  int pre = partial[blockIdx.x] + lds[tid] - s;
#pragma unroll
  for (int j = 0; j < 4; ++j) {
    int i = base + j;
    if (i < n) {
      row_start[i] = pre;
      pre += d[j];
    }
  }
}

__global__ void fill_kernel(const int* __restrict__ src, const int* __restrict__ dst,
                            const int* __restrict__ row_start, int* __restrict__ cursor,
                            int* __restrict__ esrc, int E) {
  int i = blockIdx.x * blockDim.x + threadIdx.x;
  if (i < E) {
    int d = dst[i];
    int pos = atomicAdd(&cursor[d], 1);
    esrc[row_start[d] + pos] = src[i];
  }
}

// ----------------------------------------------------- fused SAGE layer
// Block = 64 nodes, 4 waves, wave w owns output rows 16w..16w+15.
// GATHER (8-lane groups): group g handles nodes m0+2g, m0+2g+1 -> writes mt
// rows 2g, 2g+1. Wave w = groups 8w..8w+7 -> own rows 16w..16w+15 only, so NO
// barrier before the wave reads its am fragments back (same-wave lgkmcnt).
// 8-lane groups (32 B/lane) double per-lane bytes-in-flight and halve the
// serial node chain vs 16-lane groups (round-1 structure).
// WEIGHTS: B-fragments preloaded in bulk into registers (16 frags = 64 VGPR
// per panel, two ping-pong buffers). Round-2 failure: per-MFMA global loads
// serialized at L2 latency (VGPR=68 showed no hoisting). Bulk hoist = 16
// concurrent loads per panel, first panel issued BEFORE gather so its latency
// hides. Zero barriers until the epilogue transpose.
// EPILOGUE: coalesced via LDS transpose (scattered 2B stores cost 2x write amp).
// PRED variant (layer 3): keep h3 in LDS, two more weight matrices produce
// A = h3@WtA + biasA and B = h3@WtB directly (h3 never hits HBM).
template <bool PRED>
__global__ __launch_bounds__(256) void layer_fused(
    const unsigned short* __restrict__ hin,
    const int* __restrict__ row_start, const int* __restrict__ esrc,
    const unsigned short* __restrict__ Wts, const unsigned short* __restrict__ Wtn,
    const float* __restrict__ bias,
    const unsigned short* __restrict__ WtA, const unsigned short* __restrict__ WtB,
    const float* __restrict__ biasA,
    unsigned short* __restrict__ out0, unsigned short* __restrict__ out1, int M) {
  __shared__ unsigned short mt[64][136];   // 17.4 KB mean tile (reused: h3 tile, epilogue tile)
  const int tid = threadIdx.x;
  const int lane = tid & 63;
  const int wave = tid >> 6;
  const int m0 = blockIdx.x * 64;
  const int row = lane & 15;
  const int q = lane >> 4;
  const int mw = m0 + wave * 16;
  const int mload = min(mw + row, M - 1);

  // per-lane base offset into a transposed weight matrix (shorts):
  // frag(W,half,t,s) = W[(half*64 + t*16 + row)*D + s*32 + q*8]
  const size_t wb = (size_t)row * D + q * 8;

  // bulk-load the 16 B-frags of one half-n panel into registers
  auto load_frags = [&](const unsigned short* Wt, int half, bf16x8* fr) {
#pragma unroll
    for (int s = 0; s < 4; ++s)
#pragma unroll
      for (int t = 0; t < 4; ++t)
        fr[s * 4 + t] = *reinterpret_cast<const bf16x8*>(
            Wt + wb + (size_t)(half * 64 + t * 16) * D + s * 32);
  };
  // 16 MFMAs of one half-n panel from register frags
  auto mfma_regs = [&](bf16x8* a, bf16x8* fr, f32x4* accp) {
#pragma unroll
    for (int s = 0; s < 4; ++s)
#pragma unroll
      for (int t = 0; t < 4; ++t)
        accp[t] = __builtin_amdgcn_mfma_f32_16x16x32_bf16(a[s], fr[s * 4 + t], accp[t], 0, 0, 0);
  };
  // coalesced epilogue: acc (+bias) -> mt own rows -> barrier -> uint4 stores.
  auto epilogue = [&](f32x4* accp, const float* bvec, unsigned short* dst) {
#pragma unroll
    for (int t = 0; t < 8; ++t) {
      const int col = t * 16 + row;
      const float bv = bvec ? bvec[col] : 0.f;
#pragma unroll
      for (int r = 0; r < 4; ++r)
        mt[wave * 16 + q * 4 + r][col] = f32_to_bf16(accp[t][r] + bv);
    }
    __syncthreads();
    // full tile = 64 rows x 16 chunks of 16B = 1024 chunks, 4 per thread
#pragma unroll
    for (int i = 0; i < 4; ++i) {
      int idx = i * 256 + tid;
      int r2 = idx >> 4;
      int c8 = (idx & 15) * 8;
      int m = m0 + r2;
      if (m < M)
        *reinterpret_cast<uint4*>(dst + (size_t)m * D + c8) =
            *reinterpret_cast<const uint4*>(&mt[r2][c8]);
    }
  };

  // ---- A fragments of hin ----
  bf16x8 ah[4];
#pragma unroll
  for (int s = 0; s < 4; ++s)
    ah[s] = *reinterpret_cast<const bf16x8*>(hin + (size_t)mload * D + s * 32 + q * 8);

  // ---- issue first weight panel NOW: latency hides under the gather ----
  bf16x8 w0[16], w1[16];
  load_frags(Wts, 0, w0);

  // ---- phase 1: gather means into mt own rows. 8-lane group per 2 nodes ----
  {
    const int g = tid >> 3;   // 0..31
    const int fl = tid & 7;   // 32 B per lane
    const int coff = fl * 16; // short offset
    int nA = min(m0 + g * 2, M - 1);
    int nB = min(m0 + g * 2 + 1, M - 1);
    int sA0 = row_start[nA], sA1 = row_start[nA + 1];
    int sB0 = row_start[nB], sB1 = row_start[nB + 1];
    int s0a[2]; s0a[0] = sA0; s0a[1] = sB0;
    int s1a[2]; s1a[0] = sA1; s1a[1] = sB1;
#pragma unroll
    for (int j = 0; j < 2; ++j) {
      const int s0 = s0a[j], s1 = s1a[j];
      float ac[16];
#pragma unroll
      for (int k = 0; k < 16; ++k) ac[k] = 0.f;
      int e = s0;
      for (; e + 4 <= s1; e += 4) {
        int i0 = esrc[e], i1 = esrc[e + 1], i2 = esrc[e + 2], i3 = esrc[e + 3];
        const unsigned short* p0 = hin + ((size_t)i0 << 7) + coff;
        const unsigned short* p1 = hin + ((size_t)i1 << 7) + coff;
        const unsigned short* p2 = hin + ((size_t)i2 << 7) + coff;
        const unsigned short* p3 = hin + ((size_t)i3 << 7) + coff;
        uint4 r0a = *(const uint4*)(p0);     uint4 r0b = *(const uint4*)(p0 + 8);
        uint4 r1a = *(const uint4*)(p1);     uint4 r1b = *(const uint4*)(p1 + 8);
        uint4 r2a = *(const uint4*)(p2);     uint4 r2b = *(const uint4*)(p2 + 8);
        uint4 r3a = *(const uint4*)(p3);     uint4 r3b = *(const uint4*)(p3 + 8);
        acc8(ac, r0a); acc8(ac + 8, r0b);
        acc8(ac, r1a); acc8(ac + 8, r1b);
        acc8(ac, r2a); acc8(ac + 8, r2b);
        acc8(ac, r3a); acc8(ac + 8, r3b);
      }
      for (; e < s1; ++e) {
        const unsigned short* p0 = hin + ((size_t)esrc[e] << 7) + coff;
        uint4 r0a = *(const uint4*)(p0);     uint4 r0b = *(const uint4*)(p0 + 8);
        acc8(ac, r0a); acc8(ac + 8, r0b);
      }
      const float inv = 1.0f / (float)max(s1 - s0, 1);
#pragma unroll
      for (int k = 0; k < 16; ++k) ac[k] *= inv;
      uint4 oa, ob;
      oa.x = (unsigned)f32_to_bf16(ac[0]) | ((unsigned)f32_to_bf16(ac[1]) << 16);
      oa.y = (unsigned)f32_to_bf16(ac[2]) | ((unsigned)f32_to_bf16(ac[3]) << 16);
      oa.z = (unsigned)f32_to_bf16(ac[4]) | ((unsigned)f32_to_bf16(ac[5]) << 16);
      oa.w = (unsigned)f32_to_bf16(ac[6]) | ((unsigned)f32_to_bf16(ac[7]) << 16);
      ob.x = (unsigned)f32_to_bf16(ac[8]) | ((unsigned)f32_to_bf16(ac[9]) << 16);
      ob.y = (unsigned)f32_to_bf16(ac[10]) | ((unsigned)f32_to_bf16(ac[11]) << 16);
      ob.z = (unsigned)f32_to_bf16(ac[12]) | ((unsigned)f32_to_bf16(ac[13]) << 16);
      ob.w = (unsigned)f32_to_bf16(ac[14]) | ((unsigned)f32_to_bf16(ac[15]) << 16);
      const int lr = g * 2 + j;
      *reinterpret_cast<uint4*>(&mt[lr][coff]) = oa;
      *reinterpret_cast<uint4*>(&mt[lr][coff + 8]) = ob;
    }
  }
  // NO barrier: each wave reads back only the mt rows it wrote.

  // ---- second panel in flight, then mean A-fragments from LDS (own rows) ----
  load_frags(Wts, 1, w1);
  const int lrow = wave * 16 + row;  // local row 0..63
  bf16x8 am[4];
#pragma unroll
  for (int s = 0; s < 4; ++s)
    am[s] = *reinterpret_cast<const bf16x8*>(&mt[lrow][s * 32 + q * 8]);

  f32x4 acc[8];
#pragma unroll
  for (int t = 0; t < 8; ++t) acc[t] = (f32x4){0.f, 0.f, 0.f, 0.f};

  mfma_regs(ah, w0, acc);            // hin @ Ws, n 0..63
  load_frags(Wtn, 0, w0);
  mfma_regs(ah, w1, acc + 4);        // hin @ Ws, n 64..127
  load_frags(Wtn, 1, w1);
  mfma_regs(am, w0, acc);            // mean @ Wn, n 0..63
  mfma_regs(am, w1, acc + 4);        // mean @ Wn, n 64..127

  if (!PRED) {
    epilogue(acc, bias, out0);
    return;
  }

  // ================= PRED tail (layer 3) =================
  // issue WtA panels first so they fly under the h3 pack/ds traffic
  load_frags(WtA, 0, w0);
  load_frags(WtA, 1, w1);
  // h3 (bf16, bias applied) -> mt own rows, ap from own rows -- no barrier.
#pragma unroll
  for (int t = 0; t < 8; ++t) {
    const int col = t * 16 + row;
    const float bv = bias[col];
#pragma unroll
    for (int r = 0; r < 4; ++r)
      mt[wave * 16 + q * 4 + r][col] = f32_to_bf16(acc[t][r] + bv);
  }
  bf16x8 ap[4];
#pragma unroll
  for (int s = 0; s < 4; ++s)
    ap[s] = *reinterpret_cast<const bf16x8*>(&mt[lrow][s * 32 + q * 8]);

#pragma unroll
  for (int t = 0; t < 8; ++t) acc[t] = (f32x4){0.f, 0.f, 0.f, 0.f};
  mfma_regs(ap, w0, acc);            // h3 @ WtA, n 0..63
  mfma_regs(ap, w1, acc + 4);        // h3 @ WtA, n 64..127
  epilogue(acc, biasA, out0);        // Ab coalesced (contains a barrier)
  load_frags(WtB, 0, w0);            // hide under epilogue stores
  load_frags(WtB, 1, w1);
  __syncthreads();  // all waves' epilogue-A mt reads done before overwrite
#pragma unroll
  for (int t = 0; t < 8; ++t) acc[t] = (f32x4){0.f, 0.f, 0.f, 0.f};
  mfma_regs(ap, w0, acc);            // h3 @ WtB, n 0..63
  mfma_regs(ap, w1, acc + 4);        // h3 @ WtB, n 64..127
  epilogue(acc, nullptr, out1);      // Bb coalesced
}

// ----------------------------------------------------- edge MLP score, 4 edges / 16-lane group
// score = relu(A[s]+B[d]).Wp2 + bp2  (bp1 folded into A). 8 row-gathers in
// flight per group, int4 index loads, one coalesced float4 store per group.
__device__ __forceinline__ float relu_dot8(uint4 a, uint4 b, float4 w0, float4 w1) {
  return fmaxf(bf16_lo(a.x) + bf16_lo(b.x), 0.f) * w0.x +
         fmaxf(bf16_hi(a.x) + bf16_hi(b.x), 0.f) * w0.y +
         fmaxf(bf16_lo(a.y) + bf16_lo(b.y), 0.f) * w0.z +
         fmaxf(bf16_hi(a.y) + bf16_hi(b.y), 0.f) * w0.w +
         fmaxf(bf16_lo(a.z) + bf16_lo(b.z), 0.f) * w1.x +
         fmaxf(bf16_hi(a.z) + bf16_hi(b.z), 0.f) * w1.y +
         fmaxf(bf16_lo(a.w) + bf16_lo(b.w), 0.f) * w1.z +
         fmaxf(bf16_hi(a.w) + bf16_hi(b.w), 0.f) * w1.w;
}

__global__ __launch_bounds__(256) void edge_score4(
    const unsigned short* __restrict__ A, const unsigned short* __restrict__ B,
    const int* __restrict__ ss, const int* __restrict__ dd,
    const float* __restrict__ Wp2, const float* __restrict__ bp2,
    float* __restrict__ out, int E) {
  const int t = blockIdx.x * blockDim.x + threadIdx.x;
  const int g = t >> 4;                 // 16 lanes per 4 edges
  const int fl = t & 15;
  const int e0 = g * 4;
  if (e0 >= E) return;
  const int4 s4 = *(const int4*)(ss + e0);
  const int4 d4 = *(const int4*)(dd + e0);
  const float4 w0 = *(const float4*)(Wp2 + fl * 8);
  const float4 w1 = *(const float4*)(Wp2 + fl * 8 + 4);
  const size_t fo = (size_t)(fl * 8);

  uint4 a0 = *(const uint4*)(A + (((size_t)s4.x << 7) + fo));
  uint4 b0 = *(const uint4*)(B + (((size_t)d4.x << 7) + fo));
  uint4 a1 = *(const uint4*)(A + (((size_t)s4.y << 7) + fo));
  uint4 b1 = *(const uint4*)(B + (((size_t)d4.y << 7) + fo));
  uint4 a2 = *(const uint4*)(A + (((size_t)s4.z << 7) + fo));
  uint4 b2 = *(const uint4*)(B + (((size_t)d4.z << 7) + fo));
  uint4 a3 = *(const uint4*)(A + (((size_t)s4.w << 7) + fo));
  uint4 b3 = *(const uint4*)(B + (((size_t)d4.w << 7) + fo));

  float p0 = relu_dot8(a0, b0, w0, w1);
  float p1 = relu_dot8(a1, b1, w0, w1);
  float p2 = relu_dot8(a2, b2, w0, w1);
  float p3 = relu_dot8(a3, b3, w0, w1);

  p0 += __shfl_xor(p0, 1); p1 += __shfl_xor(p1, 1); p2 += __shfl_xor(p2, 1); p3 += __shfl_xor(p3, 1);
  p0 += __shfl_xor(p0, 2); p1 += __shfl_xor(p1, 2); p2 += __shfl_xor(p2, 2); p3 += __shfl_xor(p3, 2);
  p0 += __shfl_xor(p0, 4); p1 += __shfl_xor(p1, 4); p2 += __shfl_xor(p2, 4); p3 += __shfl_xor(p3, 4);
  p0 += __shfl_xor(p0, 8); p1 += __shfl_xor(p1, 8); p2 += __shfl_xor(p2, 8); p3 += __shfl_xor(p3, 8);

  if (fl == 0) {
    const float bv = bp2[0];
    *reinterpret_cast<float4*>(out + e0) = make_float4(p0 + bv, p1 + bv, p2 + bv, p3 + bv);
  }
}

// ---------------------------------------------------------------- launcher
extern "C" void kernel_launch(void* const* d_in, const int* in_sizes, int n_in,
                              void* d_out, int out_size, void* d_ws, size_t ws_size,
                              hipStream_t stream) {
  const float* x = (const float*)d_in[0];
  const int* src = (const int*)d_in[1];
  const int* dst = (const int*)d_in[2];
  const int* nsrc = (const int*)d_in[3];
  const int* ndst = (const int*)d_in[4];
  const float* Ws1 = (const float*)d_in[5];
  const float* Wn1 = (const float*)d_in[6];
  const float* b1 = (const float*)d_in[7];
  const float* Ws2 = (const float*)d_in[8];
  const float* Wn2 = (const float*)d_in[9];
  const float* b2 = (const float*)d_in[10];
  const float* Ws3 = (const float*)d_in[11];
  const float* Wn3 = (const float*)d_in[12];
  const float* b3 = (const float*)d_in[13];
  const float* Wp1 = (const float*)d_in[14];
  const float* bp1 = (const float*)d_in[15];
  const float* Wp2 = (const float*)d_in[16];
  const float* bp2 = (const float*)d_in[17];
  float* out = (float*)d_out;

  char* ws = (char*)d_ws;
  size_t off = 0;
  auto alloc = [&](size_t bytes) -> void* {
    void* p = ws + off;
    off += (bytes + 255) & ~(size_t)255;
    return p;
  };
  const size_t NODE_F32 = sizeof(float) * (size_t)N_NODES * D;  // 51.2 MB
  char* region0 = (char*)alloc(NODE_F32);   // bf16 xb | (spare) -> later bf16 Ab | Bb
  char* region1 = (char*)alloc(NODE_F32);   // bf16 hA | hB
  int* row_start = (int*)alloc(sizeof(int) * (N_NODES + 1));
  int* deg = (int*)alloc(sizeof(int) * N_NODES * 2);  // deg + cursor
  int* cursor = deg + N_NODES;
  int* esrc = (int*)alloc(sizeof(int) * N_EDGES);
  int* partial = (int*)alloc(sizeof(int) * 128);
  unsigned short* wt = (unsigned short*)alloc(sizeof(unsigned short) * 8 * D * D);
  (void)ws_size;

  unsigned short* xb = (unsigned short*)region0;
  unsigned short* hA = (unsigned short*)region1;
  unsigned short* hB = hA + (size_t)N_NODES * D;
  unsigned short* Ab = xb;                              // xb dead after layer-1 kernel
  unsigned short* Bb = xb + (size_t)N_NODES * D;        // second half of region0 (unused otherwise)

  // ---- conversions
  f32_to_bf16_vec<<<(N_NODES * D / 4 + 255) / 256, 256, 0, stream>>>(x, xb, N_NODES * D / 4);
  transpose_w<<<512, 256, 0, stream>>>(Ws1, Wn1, Ws2, Wn2, Ws3, Wn3, Wp1, Wp1 + D * D, wt);

  // ---- CSR build (pos edges; reused by all 3 layers)
  zero_i32<<<(2 * N_NODES + 255) / 256, 256, 0, stream>>>(deg, 2 * N_NODES);
  hist_kernel<<<(N_EDGES + 255) / 256, 256, 0, stream>>>(dst, deg, N_EDGES);
  scan_blocksum<<<SCAN_BLOCKS, 256, 0, stream>>>(deg, partial, N_NODES);
  scan_offsets<<<1, 128, 0, stream>>>(partial, row_start, SCAN_BLOCKS, N_NODES);
  scan_final<<<SCAN_BLOCKS, 256, 0, stream>>>(deg, partial, row_start, N_NODES);
  fill_kernel<<<(N_EDGES + 255) / 256, 256, 0, stream>>>(src, dst, row_start, cursor, esrc, N_EDGES);

  const int layerBlocks = (N_NODES + 63) / 64;
  const int edgeBlocks = (N_EDGES / 4 * 16) / 256;  // 16 lanes per 4 edges = 10000

  // ---- layer 1: h1 = x@Ws1 + mean(x)@Wn1 + b1  (mean via LDS)
  layer_fused<false><<<layerBlocks, 256, 0, stream>>>(
      xb, row_start, esrc, wt, wt + 16384, b1, nullptr, nullptr, nullptr, hA, nullptr, N_NODES);
  // ---- layer 2
  layer_fused<false><<<layerBlocks, 256, 0, stream>>>(
      hA, row_start, esrc, wt + 2 * 16384, wt + 3 * 16384, b2, nullptr, nullptr, nullptr, hB, nullptr, N_NODES);
  // ---- layer 3 + predictor: Ab = h3@Wp1_top + bp1, Bb = h3@Wp1_bot (h3 never leaves LDS)
  layer_fused<true><<<layerBlocks, 256, 0, stream>>>(
      hB, row_start, esrc, wt + 4 * 16384, wt + 5 * 16384, b3, wt + 6 * 16384, wt + 7 * 16384, bp1,
      Ab, Bb, N_NODES);
  // ---- edge scores: pos then neg (independent; disjoint outputs)
  edge_score4<<<edgeBlocks, 256, 0, stream>>>(Ab, Bb, src, dst, Wp2, bp2, out, N_EDGES);
  edge_score4<<<edgeBlocks, 256, 0, stream>>>(Ab, Bb, nsrc, ndst, Wp2, bp2, out + N_EDGES, N_EDGES);
}

// Round 5
// 456.967 us; speedup vs baseline: 1.3376x; 1.3147x over previous
//
#include <hip/hip_runtime.h>

#define N_NODES 100000
#define N_EDGES 640000
#define D 128
#define SCAN_TILE 1024
#define SCAN_BLOCKS ((N_NODES + SCAN_TILE - 1) / SCAN_TILE)  // 98

typedef __attribute__((ext_vector_type(8))) short bf16x8;   // 8 bf16 = 4 VGPRs
typedef __attribute__((ext_vector_type(4))) float f32x4;

__device__ __forceinline__ unsigned short f32_to_bf16(float f) {
  union { float f; unsigned int u; } v; v.f = f;
  unsigned int u = v.u;
  unsigned int r = (u + 0x7fffu + ((u >> 16) & 1u)) >> 16;  // RNE
  return (unsigned short)r;
}
__device__ __forceinline__ float bf16_lo(unsigned int u) { return __uint_as_float(u << 16); }
__device__ __forceinline__ float bf16_hi(unsigned int u) { return __uint_as_float(u & 0xffff0000u); }

__device__ __forceinline__ void acc8(float* a, uint4 r) {
  a[0] += bf16_lo(r.x); a[1] += bf16_hi(r.x);
  a[2] += bf16_lo(r.y); a[3] += bf16_hi(r.y);
  a[4] += bf16_lo(r.z); a[5] += bf16_hi(r.z);
  a[6] += bf16_lo(r.w); a[7] += bf16_hi(r.w);
}

// ---------------------------------------------------------------- utilities
__global__ void zero_i32(int* __restrict__ p, int n) {
  int i = blockIdx.x * blockDim.x + threadIdx.x;
  if (i < n) p[i] = 0;
}

__global__ void f32_to_bf16_vec(const float* __restrict__ in, unsigned short* __restrict__ out, int n4) {
  int i = blockIdx.x * blockDim.x + threadIdx.x;
  if (i < n4) {
    float4 v = ((const float4*)in)[i];
    ushort4 o;
    o.x = f32_to_bf16(v.x); o.y = f32_to_bf16(v.y);
    o.z = f32_to_bf16(v.z); o.w = f32_to_bf16(v.w);
    ((ushort4*)out)[i] = o;
  }
}

// 8 weight matrices [128x128] fp32 row-major [k][n] -> bf16 transposed Wt[n][k]
__global__ void transpose_w(const float* __restrict__ W0, const float* __restrict__ W1,
                            const float* __restrict__ W2, const float* __restrict__ W3,
                            const float* __restrict__ W4, const float* __restrict__ W5,
                            const float* __restrict__ W6, const float* __restrict__ W7,
                            unsigned short* __restrict__ wt) {
  int id = blockIdx.x * 256 + threadIdx.x;  // 512 blocks x 256 = 131072
  int mat = id >> 14;
  int rem = id & 16383;
  int n = rem >> 7, k = rem & 127;
  const float* Wm = mat < 4 ? (mat < 2 ? (mat == 0 ? W0 : W1) : (mat == 2 ? W2 : W3))
                            : (mat < 6 ? (mat == 4 ? W4 : W5) : (mat == 6 ? W6 : W7));
  wt[id] = f32_to_bf16(Wm[k * D + n]);
}

// ------------------------------------------------------------- CSR building (pos edges only)
__global__ void hist_kernel(const int* __restrict__ dst, int* __restrict__ deg, int E) {
  int i = blockIdx.x * blockDim.x + threadIdx.x;
  if (i < E) atomicAdd(&deg[dst[i]], 1);
}

__global__ void scan_blocksum(const int* __restrict__ deg, int* __restrict__ partial, int n) {
  __shared__ int lds[256];
  const int tid = threadIdx.x;
  const int base = blockIdx.x * SCAN_TILE + tid * 4;
  int s = 0;
#pragma unroll
  for (int j = 0; j < 4; ++j) {
    int i = base + j;
    if (i < n) s += deg[i];
  }
  lds[tid] = s;
  __syncthreads();
  for (int off = 128; off > 0; off >>= 1) {
    if (tid < off) lds[tid] += lds[tid + off];
    __syncthreads();
  }
  if (tid == 0) partial[blockIdx.x] = lds[0];
}

__global__ void scan_offsets(int* __restrict__ partial, int* __restrict__ row_start, int nb, int n) {
  __shared__ int lds[128];
  const int tid = threadIdx.x;
  int v = (tid < nb) ? partial[tid] : 0;
  lds[tid] = v;
  __syncthreads();
  for (int off = 1; off < 128; off <<= 1) {
    int t = (tid >= off) ? lds[tid - off] : 0;
    __syncthreads();
    lds[tid] += t;
    __syncthreads();
  }
  if (tid < nb) partial[tid] = (tid == 0) ? 0 : lds[tid - 1];
  if (tid == 0) row_start[n] = lds[nb - 1];
}

__global__ void scan_final(const int* __restrict__ deg, const int* __restrict__ partial,
                           int* __restrict__ row_start, int n) {
  __shared__ int lds[256];
  const int tid = threadIdx.x;
  const int base = blockIdx.x * SCAN_TILE + tid * 4;
  int d[4];
  int s = 0;
#pragma unroll
  for (int j = 0; j < 4; ++j) {
    int i = base + j;
    d[j] = (i < n) ? deg[i] : 0;
    s += d[j];
  }
  lds[tid] = s;
  __syncthreads();
  for (int off = 1; off < 256; off <<= 1) {
    int t = (tid >= off) ? lds[tid - off] : 0;
    __syncthreads();
    lds[tid] += t;
    __syncthreads();
  }
  int pre = partial[blockIdx.x] + lds[tid] - s;
#pragma unroll
  for (int j = 0; j < 4; ++j) {
    int i = base + j;
    if (i < n) {
      row_start[i] = pre;
      pre += d[j];
    }
  }
}

__global__ void fill_kernel(const int* __restrict__ src, const int* __restrict__ dst,
                            const int* __restrict__ row_start, int* __restrict__ cursor,
                            int* __restrict__ esrc, int E) {
  int i = blockIdx.x * blockDim.x + threadIdx.x;
  if (i < E) {
    int d = dst[i];
    int pos = atomicAdd(&cursor[d], 1);
    esrc[row_start[d] + pos] = src[i];
  }
}

// ----------------------------------------------------- gather-only mean kernel
// One node per 16-lane group, 16 nodes per 256-thread block -> 6250 blocks.
// No LDS, no MFMA, low VGPR: occupancy-driven TLP is the latency hiding
// (rounds 1/2/4: fused kernel capped at ~2 blocks/CU resident with a serial
// gather chain -> latency-bound at 12-21% HBM). Writes mean bf16 coalesced.
__global__ __launch_bounds__(256) void gather_mean(
    const unsigned short* __restrict__ hin,
    const int* __restrict__ row_start, const int* __restrict__ esrc,
    unsigned short* __restrict__ mean, int M) {
  const int t = blockIdx.x * blockDim.x + threadIdx.x;
  const int node = t >> 4;
  const int fl = t & 15;  // 16 B of the row per lane
  if (node >= M) return;
  const int s0 = row_start[node], s1 = row_start[node + 1];
  float ac[8] = {0.f, 0.f, 0.f, 0.f, 0.f, 0.f, 0.f, 0.f};
  int e = s0;
  for (; e + 4 <= s1; e += 4) {
    int i0 = esrc[e], i1 = esrc[e + 1], i2 = esrc[e + 2], i3 = esrc[e + 3];
    uint4 r0 = *(const uint4*)(hin + (((size_t)i0) << 7) + fl * 8);
    uint4 r1 = *(const uint4*)(hin + (((size_t)i1) << 7) + fl * 8);
    uint4 r2 = *(const uint4*)(hin + (((size_t)i2) << 7) + fl * 8);
    uint4 r3 = *(const uint4*)(hin + (((size_t)i3) << 7) + fl * 8);
    acc8(ac, r0); acc8(ac, r1); acc8(ac, r2); acc8(ac, r3);
  }
  for (; e < s1; ++e) {
    uint4 r0 = *(const uint4*)(hin + (((size_t)esrc[e]) << 7) + fl * 8);
    acc8(ac, r0);
  }
  const float inv = 1.0f / (float)max(s1 - s0, 1);
#pragma unroll
  for (int k = 0; k < 8; ++k) ac[k] *= inv;
  uint4 o;
  o.x = (unsigned)f32_to_bf16(ac[0]) | ((unsigned)f32_to_bf16(ac[1]) << 16);
  o.y = (unsigned)f32_to_bf16(ac[2]) | ((unsigned)f32_to_bf16(ac[3]) << 16);
  o.z = (unsigned)f32_to_bf16(ac[4]) | ((unsigned)f32_to_bf16(ac[5]) << 16);
  o.w = (unsigned)f32_to_bf16(ac[6]) | ((unsigned)f32_to_bf16(ac[7]) << 16);
  *reinterpret_cast<uint4*>(mean + (((size_t)node) << 7) + fl * 8) = o;
}

// ----------------------------------------------------- dense MLP kernel (round-1 structure, gather removed)
// Block = 64 nodes, 4 waves, wave w owns output rows 16w..16w+15.
// out = hin@Ws + mean@Wn + b via MFMA; half-n weight panels staged in LDS
// (round-1's proven 80us structure; rounds 2/4 global/register weights both
// regressed to ~145us). ah/am stream coalesced from global -> pure streaming
// GEMM, ~77 MB traffic, ~15us floor.
// EPILOGUE: coalesced via LDS transpose (scattered 2B stores = 2x write amp).
// PRED variant (layer 3): keep h3 in LDS, two more weight matrices produce
// A = h3@WtA + biasA and B = h3@WtB directly (h3 never hits HBM).
template <bool PRED>
__global__ __launch_bounds__(256) void layer_mlp(
    const unsigned short* __restrict__ hin,
    const unsigned short* __restrict__ mean,
    const unsigned short* __restrict__ Wts, const unsigned short* __restrict__ Wtn,
    const float* __restrict__ bias,
    const unsigned short* __restrict__ WtA, const unsigned short* __restrict__ WtB,
    const float* __restrict__ biasA,
    unsigned short* __restrict__ out0, unsigned short* __restrict__ out1, int M) {
  __shared__ unsigned short wl[64][136];   // 17.4 KB half-n weight panel
  __shared__ unsigned short mt[64][136];   // 17.4 KB epilogue/h3 tile
  const int tid = threadIdx.x;
  const int lane = tid & 63;
  const int wave = tid >> 6;
  const int m0 = blockIdx.x * 64;
  const int row = lane & 15;
  const int q = lane >> 4;
  const int mw = m0 + wave * 16;
  const int mload = min(mw + row, M - 1);
  const int lrow = wave * 16 + row;  // local row 0..63

  // stage rows [half*64, half*64+64) of a transposed weight matrix into wl
  auto stage64 = [&](const unsigned short* W, int half) {
#pragma unroll
    for (int i = 0; i < 4; ++i) {
      int seg = i * 256 + tid;
      int r = seg >> 4, o = (seg & 15) * 8;
      *reinterpret_cast<bf16x8*>(&wl[r][o]) =
          *reinterpret_cast<const bf16x8*>(W + (size_t)(half * 64 + r) * D + o);
    }
  };
  // 16 MFMAs of one half-panel into acc[base..base+3]
  auto mfma_half = [&](bf16x8* a, f32x4* accp) {
#pragma unroll
    for (int s = 0; s < 4; ++s)
#pragma unroll
      for (int t = 0; t < 4; ++t) {
        bf16x8 b = *reinterpret_cast<const bf16x8*>(&wl[t * 16 + row][s * 32 + q * 8]);
        accp[t] = __builtin_amdgcn_mfma_f32_16x16x32_bf16(a[s], b, accp[t], 0, 0, 0);
      }
  };
  // coalesced epilogue: acc (+bias) -> mt -> barrier -> contiguous uint4 stores.
  auto epilogue = [&](f32x4* accp, const float* bvec, unsigned short* dst) {
#pragma unroll
    for (int t = 0; t < 8; ++t) {
      const int col = t * 16 + row;
      const float bv = bvec ? bvec[col] : 0.f;
#pragma unroll
      for (int r = 0; r < 4; ++r)
        mt[wave * 16 + q * 4 + r][col] = f32_to_bf16(accp[t][r] + bv);
    }
    __syncthreads();
    // full tile = 64 rows x 16 chunks of 16B = 1024 chunks, 4 per thread
#pragma unroll
    for (int i = 0; i < 4; ++i) {
      int idx = i * 256 + tid;
      int r2 = idx >> 4;
      int c8 = (idx & 15) * 8;
      int m = m0 + r2;
      if (m < M)
        *reinterpret_cast<uint4*>(dst + (size_t)m * D + c8) =
            *reinterpret_cast<const uint4*>(&mt[r2][c8]);
    }
  };

  // ---- stage Ws half 0; A fragments stream in under the staging ----
  stage64(Wts, 0);
  bf16x8 ah[4], am[4];
#pragma unroll
  for (int s = 0; s < 4; ++s) {
    ah[s] = *reinterpret_cast<const bf16x8*>(hin + (size_t)mload * D + s * 32 + q * 8);
    am[s] = *reinterpret_cast<const bf16x8*>(mean + (size_t)mload * D + s * 32 + q * 8);
  }
  __syncthreads();

  f32x4 acc[8];
#pragma unroll
  for (int t = 0; t < 8; ++t) acc[t] = (f32x4){0.f, 0.f, 0.f, 0.f};

  mfma_half(ah, acc);                 // hin @ Ws, n 0..63
  __syncthreads(); stage64(Wts, 1); __syncthreads();
  mfma_half(ah, acc + 4);             // hin @ Ws, n 64..127
  __syncthreads(); stage64(Wtn, 0); __syncthreads();
  mfma_half(am, acc);                 // mean @ Wn, n 0..63
  __syncthreads(); stage64(Wtn, 1); __syncthreads();
  mfma_half(am, acc + 4);             // mean @ Wn, n 64..127

  if (!PRED) {
    epilogue(acc, bias, out0);
    return;
  }

  // ================= PRED tail (layer 3) =================
  __syncthreads();  // all waves done with wl(Wtn half1) before restage
  // ---- h3 (bf16, bias applied) into mt own rows; stage WtA half 0 ----
#pragma unroll
  for (int t = 0; t < 8; ++t) {
    const int col = t * 16 + row;
    const float bv = bias[col];
#pragma unroll
    for (int r = 0; r < 4; ++r)
      mt[wave * 16 + q * 4 + r][col] = f32_to_bf16(acc[t][r] + bv);
  }
  stage64(WtA, 0);
  __syncthreads();
  // ---- h3 A-fragments (each wave reads only rows it wrote) ----
  bf16x8 ap[4];
#pragma unroll
  for (int s = 0; s < 4; ++s)
    ap[s] = *reinterpret_cast<const bf16x8*>(&mt[lrow][s * 32 + q * 8]);

#pragma unroll
  for (int t = 0; t < 8; ++t) acc[t] = (f32x4){0.f, 0.f, 0.f, 0.f};
  mfma_half(ap, acc);                 // h3 @ WtA, n 0..63
  __syncthreads(); stage64(WtA, 1); __syncthreads();
  mfma_half(ap, acc + 4);             // h3 @ WtA, n 64..127
  epilogue(acc, biasA, out0);         // Ab coalesced
  __syncthreads(); stage64(WtB, 0); __syncthreads();
#pragma unroll
  for (int t = 0; t < 8; ++t) acc[t] = (f32x4){0.f, 0.f, 0.f, 0.f};
  mfma_half(ap, acc);                 // h3 @ WtB, n 0..63
  __syncthreads(); stage64(WtB, 1); __syncthreads();
  mfma_half(ap, acc + 4);             // h3 @ WtB, n 64..127
  epilogue(acc, nullptr, out1);       // Bb coalesced
}

// ----------------------------------------------------- edge MLP score, 4 edges / 16-lane group
// score = relu(A[s]+B[d]).Wp2 + bp2  (bp1 folded into A). 8 row-gathers in
// flight per group, int4 index loads, one coalesced float4 store per group.
__device__ __forceinline__ float relu_dot8(uint4 a, uint4 b, float4 w0, float4 w1) {
  return fmaxf(bf16_lo(a.x) + bf16_lo(b.x), 0.f) * w0.x +
         fmaxf(bf16_hi(a.x) + bf16_hi(b.x), 0.f) * w0.y +
         fmaxf(bf16_lo(a.y) + bf16_lo(b.y), 0.f) * w0.z +
         fmaxf(bf16_hi(a.y) + bf16_hi(b.y), 0.f) * w0.w +
         fmaxf(bf16_lo(a.z) + bf16_lo(b.z), 0.f) * w1.x +
         fmaxf(bf16_hi(a.z) + bf16_hi(b.z), 0.f) * w1.y +
         fmaxf(bf16_lo(a.w) + bf16_lo(b.w), 0.f) * w1.z +
         fmaxf(bf16_hi(a.w) + bf16_hi(b.w), 0.f) * w1.w;
}

__global__ __launch_bounds__(256) void edge_score4(
    const unsigned short* __restrict__ A, const unsigned short* __restrict__ B,
    const int* __restrict__ ss, const int* __restrict__ dd,
    const float* __restrict__ Wp2, const float* __restrict__ bp2,
    float* __restrict__ out, int E) {
  const int t = blockIdx.x * blockDim.x + threadIdx.x;
  const int g = t >> 4;                 // 16 lanes per 4 edges
  const int fl = t & 15;
  const int e0 = g * 4;
  if (e0 >= E) return;
  const int4 s4 = *(const int4*)(ss + e0);
  const int4 d4 = *(const int4*)(dd + e0);
  const float4 w0 = *(const float4*)(Wp2 + fl * 8);
  const float4 w1 = *(const float4*)(Wp2 + fl * 8 + 4);
  const size_t fo = (size_t)(fl * 8);

  uint4 a0 = *(const uint4*)(A + (((size_t)s4.x << 7) + fo));
  uint4 b0 = *(const uint4*)(B + (((size_t)d4.x << 7) + fo));
  uint4 a1 = *(const uint4*)(A + (((size_t)s4.y << 7) + fo));
  uint4 b1 = *(const uint4*)(B + (((size_t)d4.y << 7) + fo));
  uint4 a2 = *(const uint4*)(A + (((size_t)s4.z << 7) + fo));
  uint4 b2 = *(const uint4*)(B + (((size_t)d4.z << 7) + fo));
  uint4 a3 = *(const uint4*)(A + (((size_t)s4.w << 7) + fo));
  uint4 b3 = *(const uint4*)(B + (((size_t)d4.w << 7) + fo));

  float p0 = relu_dot8(a0, b0, w0, w1);
  float p1 = relu_dot8(a1, b1, w0, w1);
  float p2 = relu_dot8(a2, b2, w0, w1);
  float p3 = relu_dot8(a3, b3, w0, w1);

  p0 += __shfl_xor(p0, 1); p1 += __shfl_xor(p1, 1); p2 += __shfl_xor(p2, 1); p3 += __shfl_xor(p3, 1);
  p0 += __shfl_xor(p0, 2); p1 += __shfl_xor(p1, 2); p2 += __shfl_xor(p2, 2); p3 += __shfl_xor(p3, 2);
  p0 += __shfl_xor(p0, 4); p1 += __shfl_xor(p1, 4); p2 += __shfl_xor(p2, 4); p3 += __shfl_xor(p3, 4);
  p0 += __shfl_xor(p0, 8); p1 += __shfl_xor(p1, 8); p2 += __shfl_xor(p2, 8); p3 += __shfl_xor(p3, 8);

  if (fl == 0) {
    const float bv = bp2[0];
    *reinterpret_cast<float4*>(out + e0) = make_float4(p0 + bv, p1 + bv, p2 + bv, p3 + bv);
  }
}

// ---------------------------------------------------------------- launcher
extern "C" void kernel_launch(void* const* d_in, const int* in_sizes, int n_in,
                              void* d_out, int out_size, void* d_ws, size_t ws_size,
                              hipStream_t stream) {
  const float* x = (const float*)d_in[0];
  const int* src = (const int*)d_in[1];
  const int* dst = (const int*)d_in[2];
  const int* nsrc = (const int*)d_in[3];
  const int* ndst = (const int*)d_in[4];
  const float* Ws1 = (const float*)d_in[5];
  const float* Wn1 = (const float*)d_in[6];
  const float* b1 = (const float*)d_in[7];
  const float* Ws2 = (const float*)d_in[8];
  const float* Wn2 = (const float*)d_in[9];
  const float* b2 = (const float*)d_in[10];
  const float* Ws3 = (const float*)d_in[11];
  const float* Wn3 = (const float*)d_in[12];
  const float* b3 = (const float*)d_in[13];
  const float* Wp1 = (const float*)d_in[14];
  const float* bp1 = (const float*)d_in[15];
  const float* Wp2 = (const float*)d_in[16];
  const float* bp2 = (const float*)d_in[17];
  float* out = (float*)d_out;

  char* ws = (char*)d_ws;
  size_t off = 0;
  auto alloc = [&](size_t bytes) -> void* {
    void* p = ws + off;
    off += (bytes + 255) & ~(size_t)255;
    return p;
  };
  const size_t NODE_F32 = sizeof(float) * (size_t)N_NODES * D;  // 51.2 MB
  char* region0 = (char*)alloc(NODE_F32);   // bf16 xb | (spare) -> later bf16 Ab | Bb
  char* region1 = (char*)alloc(NODE_F32);   // bf16 hA | hB
  unsigned short* meanb = (unsigned short*)alloc(sizeof(unsigned short) * (size_t)N_NODES * D);
  int* row_start = (int*)alloc(sizeof(int) * (N_NODES + 1));
  int* deg = (int*)alloc(sizeof(int) * N_NODES * 2);  // deg + cursor
  int* cursor = deg + N_NODES;
  int* esrc = (int*)alloc(sizeof(int) * N_EDGES);
  int* partial = (int*)alloc(sizeof(int) * 128);
  unsigned short* wt = (unsigned short*)alloc(sizeof(unsigned short) * 8 * D * D);
  (void)ws_size;

  unsigned short* xb = (unsigned short*)region0;
  unsigned short* hA = (unsigned short*)region1;
  unsigned short* hB = hA + (size_t)N_NODES * D;
  unsigned short* Ab = xb;                              // xb dead after layer-1 MLP
  unsigned short* Bb = xb + (size_t)N_NODES * D;        // second half of region0

  // ---- conversions
  f32_to_bf16_vec<<<(N_NODES * D / 4 + 255) / 256, 256, 0, stream>>>(x, xb, N_NODES * D / 4);
  transpose_w<<<512, 256, 0, stream>>>(Ws1, Wn1, Ws2, Wn2, Ws3, Wn3, Wp1, Wp1 + D * D, wt);

  // ---- CSR build (pos edges; reused by all 3 layers)
  zero_i32<<<(2 * N_NODES + 255) / 256, 256, 0, stream>>>(deg, 2 * N_NODES);
  hist_kernel<<<(N_EDGES + 255) / 256, 256, 0, stream>>>(dst, deg, N_EDGES);
  scan_blocksum<<<SCAN_BLOCKS, 256, 0, stream>>>(deg, partial, N_NODES);
  scan_offsets<<<1, 128, 0, stream>>>(partial, row_start, SCAN_BLOCKS, N_NODES);
  scan_final<<<SCAN_BLOCKS, 256, 0, stream>>>(deg, partial, row_start, N_NODES);
  fill_kernel<<<(N_EDGES + 255) / 256, 256, 0, stream>>>(src, dst, row_start, cursor, esrc, N_EDGES);

  const int gatherBlocks = (N_NODES * 16 + 255) / 256;  // 6250
  const int mlpBlocks = (N_NODES + 63) / 64;            // 1563
  const int edgeBlocks = (N_EDGES / 4 * 16) / 256;      // 10000

  // ---- layer 1
  gather_mean<<<gatherBlocks, 256, 0, stream>>>(xb, row_start, esrc, meanb, N_NODES);
  layer_mlp<false><<<mlpBlocks, 256, 0, stream>>>(
      xb, meanb, wt, wt + 16384, b1, nullptr, nullptr, nullptr, hA, nullptr, N_NODES);
  // ---- layer 2
  gather_mean<<<gatherBlocks, 256, 0, stream>>>(hA, row_start, esrc, meanb, N_NODES);
  layer_mlp<false><<<mlpBlocks, 256, 0, stream>>>(
      hA, meanb, wt + 2 * 16384, wt + 3 * 16384, b2, nullptr, nullptr, nullptr, hB, nullptr, N_NODES);
  // ---- layer 3 + predictor
  gather_mean<<<gatherBlocks, 256, 0, stream>>>(hB, row_start, esrc, meanb, N_NODES);
  layer_mlp<true><<<mlpBlocks, 256, 0, stream>>>(
      hB, meanb, wt + 4 * 16384, wt + 5 * 16384, b3, wt + 6 * 16384, wt + 7 * 16384, bp1,
      Ab, Bb, N_NODES);
  // ---- edge scores: pos then neg (independent; disjoint outputs)
  edge_score4<<<edgeBlocks, 256, 0, stream>>>(Ab, Bb, src, dst, Wp2, bp2, out, N_EDGES);
  edge_score4<<<edgeBlocks, 256, 0, stream>>>(Ab, Bb, nsrc, ndst, Wp2, bp2, out + N_EDGES, N_EDGES);
}